// Round 6
// baseline (1334.280 us; speedup 1.0000x reference)
//
#include <hip/hip_runtime.h>
#include <math.h>

#define N_NODES 100000
#define NPAD    100064          // +64 rows tail padding for BM=64 staging
#define NFEAT 512
#define NHID 128
#define NCLASS 40

typedef unsigned int uint;
typedef unsigned short ushort;
typedef short bf16x8 __attribute__((ext_vector_type(8)));
typedef float f32x4 __attribute__((ext_vector_type(4)));

// f32 -> bf16 (RNE)
__device__ inline ushort bf16s(float a) {
    uint u = __float_as_uint(a);
    return (ushort)((u + 0x7fffu + ((u >> 16) & 1u)) >> 16);
}
__device__ inline uint bf16pack(float a, float b) {
    return (uint)bf16s(a) | ((uint)bf16s(b) << 16);
}
__device__ inline float bf16tof(ushort u) { return __uint_as_float(((uint)u) << 16); }
__device__ inline float bflo(uint u) { return __uint_as_float(u << 16); }
__device__ inline float bfhi(uint u) { return __uint_as_float(u & 0xffff0000u); }

// Sliced bf16 activation layout: [slice(8)][node(NPAD)][16 feats]
// ushort offset  = (slice*NPAD + node)*16 + (col & 15), slice = col >> 4
// uint2  offset  = (slice*NPAD + node)*4  + fl,         fl = (col&15)>>2

// ---------------------------------------------------------------------------
// weight prep: wT1[n][k] = bf16(fc1_w[k][n])   (128 x 512)
//              wTc[L][n][k] = bf16(conv_w[L][k][n])  (4 x 128 x 128)
// ---------------------------------------------------------------------------
__global__ void prep_weights(const float* __restrict__ fc1_w, const float* __restrict__ conv_w,
                             ushort* __restrict__ wT1, ushort* __restrict__ wTc) {
    int idx = blockIdx.x * 256 + threadIdx.x;   // 65536 total
    {   int n = idx >> 9, k = idx & 511;
        wT1[idx] = bf16s(fc1_w[k * NHID + n]); }
    {   int L = idx >> 14, rem = idx & 16383;
        int n = rem >> 7, k = rem & 127;
        wTc[idx] = bf16s(conv_w[L * 16384 + k * NHID + n]); }
}

// ---------------------------------------------------------------------------
// row_ptr[i] = lower_bound(rows, i)
// ---------------------------------------------------------------------------
__global__ void rowptr_kernel(const int* __restrict__ rows, int* __restrict__ rowptr, int nE) {
    int i = blockIdx.x * blockDim.x + threadIdx.x;
    if (i > N_NODES) return;
    int lo = 0, hi = nE;
    while (lo < hi) { int mid = (lo + hi) >> 1; if (rows[mid] < i) lo = mid + 1; else hi = mid; }
    rowptr[i] = lo;
}

// ---------------------------------------------------------------------------
// fc1 MFMA: h0b(sliced) = bf16(relu(x @ W + b)). BM=32, BN=128, K-step 64.
// ---------------------------------------------------------------------------
__global__ void __launch_bounds__(256) fc1_mfma(const float* __restrict__ x,
                                                const uint* __restrict__ wT1,
                                                const float* __restrict__ bias,
                                                ushort* __restrict__ h0b) {
    __shared__ ushort As[32][72];
    __shared__ ushort Bs[128][72];
    const int tid = threadIdx.x;
    const int lane = tid & 63;
    const int wave = tid >> 6;
    const int wr = wave >> 1, wc = wave & 1;
    const int r0 = blockIdx.x * 32;

    f32x4 acc[4] = {};

    for (int ks = 0; ks < NFEAT; ks += 64) {
        {   int row = tid >> 3, kq = tid & 7;
            const float* xp = x + (size_t)(r0 + row) * NFEAT + ks + kq * 8;
            float4 v0 = *reinterpret_cast<const float4*>(xp);
            float4 v1 = *reinterpret_cast<const float4*>(xp + 4);
            uint4 pk;
            pk.x = bf16pack(v0.x, v0.y); pk.y = bf16pack(v0.z, v0.w);
            pk.z = bf16pack(v1.x, v1.y); pk.w = bf16pack(v1.z, v1.w);
            *reinterpret_cast<uint4*>(&As[row][kq * 8]) = pk;
        }
        #pragma unroll
        for (int p = 0; p < 4; ++p) {
            int idx = tid + p * 256;
            int n = idx >> 3, q = idx & 7;
            uint4 w4 = *reinterpret_cast<const uint4*>(wT1 + n * 256 + (ks >> 1) + q * 4);
            *reinterpret_cast<uint4*>(&Bs[n][q * 8]) = w4;
        }
        __syncthreads();
        #pragma unroll
        for (int ks2 = 0; ks2 < 64; ks2 += 32) {
            bf16x8 a = *reinterpret_cast<const bf16x8*>(&As[wr * 16 + (lane & 15)][ks2 + (lane >> 4) * 8]);
            #pragma unroll
            for (int j = 0; j < 4; ++j) {
                bf16x8 b = *reinterpret_cast<const bf16x8*>(&Bs[wc * 64 + j * 16 + (lane & 15)][ks2 + (lane >> 4) * 8]);
                acc[j] = __builtin_amdgcn_mfma_f32_16x16x32_bf16(a, b, acc[j], 0, 0, 0);
            }
        }
        __syncthreads();
    }

    const int rb = r0 + wr * 16 + ((lane >> 4) << 2);
    #pragma unroll
    for (int j = 0; j < 4; ++j) {
        int col = wc * 64 + j * 16 + (lane & 15);
        int s = wc * 4 + j;
        float bj = bias[col];
        #pragma unroll
        for (int i = 0; i < 4; ++i) {
            float v = fmaxf(acc[j][i] + bj, 0.f);
            h0b[((size_t)s * NPAD + rb + i) * 16 + (lane & 15)] = bf16s(v);
        }
    }
}

// ---------------------------------------------------------------------------
// conv layer MFMA, BM=64, sliced A source: out = relu(theta*(S@W) + (1-theta)*S).
// Writes hb (sliced bf16) or fout (dense f32, last layer).
// ---------------------------------------------------------------------------
__global__ void __launch_bounds__(256) layer_mfma(const uint* __restrict__ sbs,
                                                  const uint* __restrict__ wTc,
                                                  float theta,
                                                  ushort* __restrict__ hb,
                                                  float* __restrict__ fout) {
    __shared__ ushort As[64][136];
    __shared__ ushort Bs[128][136];
    const int tid = threadIdx.x;
    const int lane = tid & 63;
    const int wave = tid >> 6;
    const int wr = wave >> 1, wc = wave & 1;
    const int r0 = blockIdx.x * 64;

    #pragma unroll
    for (int p = 0; p < 4; ++p) {   // stage A: 64 rows x 8 slices x 2 halves
        int idx = tid + p * 256;    // 0..1023
        int s = idx >> 7;
        int rem = idx & 127;
        int row = rem >> 1, half = rem & 1;
        uint4 v = *reinterpret_cast<const uint4*>(sbs + ((size_t)s * NPAD + r0 + row) * 8 + half * 4);
        *reinterpret_cast<uint4*>(&As[row][s * 16 + half * 8]) = v;
    }
    #pragma unroll
    for (int p = 0; p < 8; ++p) {   // stage B: 128 n x 128 k
        int idx = tid + p * 256;
        int n = idx >> 4, kq = idx & 15;
        uint4 v = *reinterpret_cast<const uint4*>(wTc + n * 64 + kq * 4);
        *reinterpret_cast<uint4*>(&Bs[n][kq * 8]) = v;
    }
    __syncthreads();

    f32x4 acc[2][4] = {};
    #pragma unroll
    for (int ks = 0; ks < NHID; ks += 32) {
        #pragma unroll
        for (int mr = 0; mr < 2; ++mr) {
            bf16x8 a = *reinterpret_cast<const bf16x8*>(&As[wr * 32 + mr * 16 + (lane & 15)][ks + (lane >> 4) * 8]);
            #pragma unroll
            for (int j = 0; j < 4; ++j) {
                bf16x8 b = *reinterpret_cast<const bf16x8*>(&Bs[wc * 64 + j * 16 + (lane & 15)][ks + (lane >> 4) * 8]);
                acc[mr][j] = __builtin_amdgcn_mfma_f32_16x16x32_bf16(a, b, acc[mr][j], 0, 0, 0);
            }
        }
    }

    const float om = 1.f - theta;
    #pragma unroll
    for (int mr = 0; mr < 2; ++mr) {
        const int rloc = wr * 32 + mr * 16 + ((lane >> 4) << 2);
        #pragma unroll
        for (int j = 0; j < 4; ++j) {
            int col = wc * 64 + j * 16 + (lane & 15);
            int s = wc * 4 + j;
            #pragma unroll
            for (int i = 0; i < 4; ++i) {
                int gr = r0 + rloc + i;
                if (gr < N_NODES) {
                    float sv = bf16tof(As[rloc + i][col]);
                    float v = fmaxf(fmaf(theta, acc[mr][j][i], om * sv), 0.f);
                    if (fout) fout[(size_t)gr * NHID + col] = v;
                    else      hb[((size_t)s * NPAD + gr) * 16 + (lane & 15)] = bf16s(v);
                }
            }
        }
    }
}

// ---------------------------------------------------------------------------
// SpMM + residual, XCD-sliced: for slice s (= blockIdx&7, lands on XCD s):
//   sbs[s][n][:] = bf16(0.9 * sum_e vals[e]*hbs[s][cols[e]][:] + 0.1*h0bs[s][n][:])
// One wave per (node, slice): 16 edge-slots x 4 feature-lanes (uint2 each).
// Slice working set = 3.2 MB -> resident in that XCD's 4 MB L2.
// ---------------------------------------------------------------------------
__global__ void __launch_bounds__(256) spmm_kernel(const uint2* __restrict__ hbs,
                                                   const uint2* __restrict__ h0bs,
                                                   const int* __restrict__ rowptr,
                                                   const int* __restrict__ cols,
                                                   const float* __restrict__ vals,
                                                   uint2* __restrict__ sbs) {
    const int slice = blockIdx.x & 7;
    const int node  = (blockIdx.x >> 3) * 4 + (threadIdx.x >> 6);
    const int lane  = threadIdx.x & 63;
    const int slot  = lane >> 2;      // edge slot 0..15
    const int fl    = lane & 3;       // feature quad within slice

    const int e0 = rowptr[node], e1 = rowptr[node + 1];
    const uint2* hrow = hbs + (size_t)slice * NPAD * 4;

    float a0 = 0.f, a1 = 0.f, a2 = 0.f, a3 = 0.f;
    #pragma unroll 2
    for (int base = e0; base < e1; base += 16) {
        int m = e1 - base; if (m > 16) m = 16;
        int c = 0; float v = 0.f;
        if (lane < m) {
            c = __builtin_nontemporal_load(cols + base + lane);
            v = __builtin_nontemporal_load(vals + base + lane);
        }
        int   cj = __shfl(c, slot);
        float vj = __shfl(v, slot);
        if (slot >= m) vj = 0.f;
        uint2 hv = hrow[(size_t)cj * 4 + fl];
        a0 = fmaf(vj, bflo(hv.x), a0);
        a1 = fmaf(vj, bfhi(hv.x), a1);
        a2 = fmaf(vj, bflo(hv.y), a2);
        a3 = fmaf(vj, bfhi(hv.y), a3);
    }
    // reduce across the 16 slots (lane bits 2..5)
    #pragma unroll
    for (int d = 4; d <= 32; d <<= 1) {
        a0 += __shfl_xor(a0, d);
        a1 += __shfl_xor(a1, d);
        a2 += __shfl_xor(a2, d);
        a3 += __shfl_xor(a3, d);
    }

    if (slot == 0) {
        size_t o = ((size_t)slice * NPAD + node) * 4 + fl;
        uint2 h0v = h0bs[o];
        uint2 w;
        w.x = bf16pack(0.9f * a0 + 0.1f * bflo(h0v.x), 0.9f * a1 + 0.1f * bfhi(h0v.x));
        w.y = bf16pack(0.9f * a2 + 0.1f * bflo(h0v.y), 0.9f * a3 + 0.1f * bfhi(h0v.y));
        sbs[o] = w;
    }
}

// ---------------------------------------------------------------------------
// final: logits = h @ fc2_w + b; out0 = log_softmax; out2 = [h, logits]
// ---------------------------------------------------------------------------
__global__ void final_kernel(const float* __restrict__ h, const float* __restrict__ w,
                             const float* __restrict__ b, float* __restrict__ out0,
                             float* __restrict__ out2) {
    __shared__ float hs[4][128];
    const int s = threadIdx.x >> 6;
    const int lane = threadIdx.x & 63;
    const int node = blockIdx.x * 4 + s;

    float h_lo = h[node * NHID + lane];
    float h_hi = h[node * NHID + 64 + lane];
    hs[s][lane] = h_lo;
    hs[s][64 + lane] = h_hi;
    __syncthreads();

    float logit = 0.f;
    if (lane < NCLASS) {
        logit = b[lane];
        #pragma unroll 8
        for (int k = 0; k < NHID; ++k)
            logit = fmaf(hs[s][k], w[k * NCLASS + lane], logit);
    }

    float mv = (lane < NCLASS) ? logit : -1e30f;
    #pragma unroll
    for (int m = 32; m; m >>= 1) mv = fmaxf(mv, __shfl_xor(mv, m));
    float ev = (lane < NCLASS) ? __expf(logit - mv) : 0.f;
    float sum = ev;
    #pragma unroll
    for (int m = 32; m; m >>= 1) sum += __shfl_xor(sum, m);
    float lse = mv + __logf(sum);

    if (lane < NCLASS) {
        out0[node * NCLASS + lane] = logit - lse;
        out2[node * 168 + 128 + lane] = logit;
    }
    out2[node * 168 + lane] = h_lo;
    out2[node * 168 + 64 + lane] = h_hi;
}

// ---------------------------------------------------------------------------
extern "C" void kernel_launch(void* const* d_in, const int* in_sizes, int n_in,
                              void* d_out, int out_size, void* d_ws, size_t ws_size,
                              hipStream_t stream) {
    const float* x      = (const float*)d_in[0];
    const int*   rows   = (const int*)  d_in[1];
    const int*   cols   = (const int*)  d_in[2];
    const float* vals   = (const float*)d_in[3];
    const float* fc1_w  = (const float*)d_in[4];
    const float* fc1_b  = (const float*)d_in[5];
    const float* conv_w = (const float*)d_in[6];
    const float* fc2_w  = (const float*)d_in[7];
    const float* fc2_b  = (const float*)d_in[8];
    float* out = (float*)d_out;

    const int nE = in_sizes[1];
    const size_t SLICED = (size_t)8 * NPAD * 16;   // elements per sliced activation

    // workspace layout
    char* p = (char*)d_ws;
    int*    rowptr = (int*)p;          p += 400128;            // 100001 ints, padded
    ushort* h0b    = (ushort*)p;       p += SLICED * 2;        // 25.6 MB sliced
    ushort* hb     = (ushort*)p;       p += SLICED * 2;        // 25.6 MB sliced
    ushort* sb     = (ushort*)p;       p += SLICED * 2;        // 25.6 MB sliced
    ushort* wT1    = (ushort*)p;       p += 65536 * 2;         // 128 KB
    ushort* wTc    = (ushort*)p;       p += 65536 * 2;         // 128 KB

    // out regions
    float* out0 = out;                                  // [N,40]
    float* out1 = out + (size_t)N_NODES * NCLASS;       // [N,128] final h (f32)
    float* out2 = out1 + (size_t)N_NODES * NHID;        // [N,168]

    prep_weights<<<256, 256, 0, stream>>>(fc1_w, conv_w, wT1, wTc);
    rowptr_kernel<<<(N_NODES + 1 + 255) / 256, 256, 0, stream>>>(rows, rowptr, nE);
    fc1_mfma<<<N_NODES / 32, 256, 0, stream>>>(x, (const uint*)wT1, fc1_b, h0b);

    for (int i = 0; i < 4; ++i) {
        float theta = logf(0.5f / (float)(i + 1) + 1.0f);
        spmm_kernel<<<(N_NODES / 4) * 8, 256, 0, stream>>>(
            (const uint2*)(i == 0 ? h0b : hb), (const uint2*)h0b, rowptr, cols, vals, (uint2*)sb);
        layer_mfma<<<(N_NODES + 63) / 64, 256, 0, stream>>>(
            (const uint*)sb, (const uint*)(wTc + (size_t)i * 16384), theta,
            (i < 3) ? hb : nullptr, (i == 3) ? out1 : nullptr);
    }

    final_kernel<<<N_NODES / 4, 256, 0, stream>>>(out1, fc2_w, fc2_b, out0, out2);
}

// Round 7
// 640.163 us; speedup vs baseline: 2.0843x; 2.0843x over previous
//
#include <hip/hip_runtime.h>
#include <math.h>

#define N_NODES 100000
#define NFEAT 512
#define NHID 128
#define NCLASS 40

typedef unsigned int uint;
typedef unsigned short ushort;
typedef short bf16x8 __attribute__((ext_vector_type(8)));
typedef float f32x4 __attribute__((ext_vector_type(4)));

// f32 -> bf16 (RNE)
__device__ inline ushort bf16s(float a) {
    uint u = __float_as_uint(a);
    return (ushort)((u + 0x7fffu + ((u >> 16) & 1u)) >> 16);
}
__device__ inline uint bf16pack(float a, float b) {
    return (uint)bf16s(a) | ((uint)bf16s(b) << 16);
}
__device__ inline float bf16tof(ushort u) { return __uint_as_float(((uint)u) << 16); }
__device__ inline float bflo(uint u) { return __uint_as_float(u << 16); }
__device__ inline float bfhi(uint u) { return __uint_as_float(u & 0xffff0000u); }

// ---------------------------------------------------------------------------
// weight prep: wT1[n][k] = bf16(fc1_w[k][n])   (128 x 512)
//              wTc[L][n][k] = bf16(conv_w[L][k][n])  (4 x 128 x 128)
// ---------------------------------------------------------------------------
__global__ void prep_weights(const float* __restrict__ fc1_w, const float* __restrict__ conv_w,
                             ushort* __restrict__ wT1, ushort* __restrict__ wTc) {
    int idx = blockIdx.x * 256 + threadIdx.x;   // 65536 total
    {   int n = idx >> 9, k = idx & 511;
        wT1[idx] = bf16s(fc1_w[k * NHID + n]); }
    {   int L = idx >> 14, rem = idx & 16383;
        int n = rem >> 7, k = rem & 127;
        wTc[idx] = bf16s(conv_w[L * 16384 + k * NHID + n]); }
}

// ---------------------------------------------------------------------------
// row_ptr[i] = lower_bound(rows, i)
// ---------------------------------------------------------------------------
__global__ void rowptr_kernel(const int* __restrict__ rows, int* __restrict__ rowptr, int nE) {
    int i = blockIdx.x * blockDim.x + threadIdx.x;
    if (i > N_NODES) return;
    int lo = 0, hi = nE;
    while (lo < hi) { int mid = (lo + hi) >> 1; if (rows[mid] < i) lo = mid + 1; else hi = mid; }
    rowptr[i] = lo;
}

// ---------------------------------------------------------------------------
// fc1 MFMA: h0b = bf16(relu(x @ W + b)). BM=32, BN=128, K=512, K-step 64.
// (R4-proven version, dense [node][128] output layout.)
// ---------------------------------------------------------------------------
__global__ void __launch_bounds__(256) fc1_mfma(const float* __restrict__ x,
                                                const uint* __restrict__ wT1,
                                                const float* __restrict__ bias,
                                                ushort* __restrict__ h0b) {
    __shared__ ushort As[32][72];
    __shared__ ushort Bs[128][72];
    const int tid = threadIdx.x;
    const int lane = tid & 63;
    const int wave = tid >> 6;
    const int wr = wave >> 1, wc = wave & 1;
    const int r0 = blockIdx.x * 32;

    f32x4 acc[4] = {};

    for (int ks = 0; ks < NFEAT; ks += 64) {
        {   int row = tid >> 3, kq = tid & 7;
            const float* xp = x + (size_t)(r0 + row) * NFEAT + ks + kq * 8;
            float4 v0 = *reinterpret_cast<const float4*>(xp);
            float4 v1 = *reinterpret_cast<const float4*>(xp + 4);
            uint4 pk;
            pk.x = bf16pack(v0.x, v0.y); pk.y = bf16pack(v0.z, v0.w);
            pk.z = bf16pack(v1.x, v1.y); pk.w = bf16pack(v1.z, v1.w);
            *reinterpret_cast<uint4*>(&As[row][kq * 8]) = pk;
        }
        #pragma unroll
        for (int p = 0; p < 4; ++p) {
            int idx = tid + p * 256;
            int n = idx >> 3, q = idx & 7;
            uint4 w4 = *reinterpret_cast<const uint4*>(wT1 + n * 256 + (ks >> 1) + q * 4);
            *reinterpret_cast<uint4*>(&Bs[n][q * 8]) = w4;
        }
        __syncthreads();
        #pragma unroll
        for (int ks2 = 0; ks2 < 64; ks2 += 32) {
            bf16x8 a = *reinterpret_cast<const bf16x8*>(&As[wr * 16 + (lane & 15)][ks2 + (lane >> 4) * 8]);
            #pragma unroll
            for (int j = 0; j < 4; ++j) {
                bf16x8 b = *reinterpret_cast<const bf16x8*>(&Bs[wc * 64 + j * 16 + (lane & 15)][ks2 + (lane >> 4) * 8]);
                acc[j] = __builtin_amdgcn_mfma_f32_16x16x32_bf16(a, b, acc[j], 0, 0, 0);
            }
        }
        __syncthreads();
    }

    const int cb = wc * 64 + (lane & 15);
    const int rb = r0 + wr * 16 + ((lane >> 4) << 2);
    #pragma unroll
    for (int j = 0; j < 4; ++j) {
        int col = cb + j * 16;
        float bj = bias[col];
        #pragma unroll
        for (int i = 0; i < 4; ++i) {
            float v = fmaxf(acc[j][i] + bj, 0.f);
            h0b[(size_t)(rb + i) * NHID + col] = bf16s(v);
        }
    }
}

// ---------------------------------------------------------------------------
// FUSED SpMM + conv layer. Per block: 64 nodes.
// Phase 1 (gather, R4-proven structure): wave w computes support rows
//   [w*16, w*16+16): sup[n,:] = 0.9 * sum_e vals[e]*hsrc[cols[e],:] + 0.1*h0[n,:]
//   quarter-split: 4 edges in flight per gather instr (16 lanes x uint4).
//   Result written as bf16 straight into the LDS A-tile (no global sb!).
// Phase 2: BM=64 MFMA GEMM from LDS: out = relu(theta*(S@W) + (1-theta)*S).
//   B staged in two 64-K halves; half 0 staged concurrently with gathers.
// ---------------------------------------------------------------------------
__global__ void __launch_bounds__(256, 4) spmm_layer(
        const uint4* __restrict__ hsrc,     // gather source, dense [node][16 uint4]
        const uint4* __restrict__ h0b4,     // residual h0, same layout
        const int* __restrict__ rowptr,
        const int* __restrict__ cols,
        const float* __restrict__ vals,
        const uint* __restrict__ wTc,       // this layer's W^T, [128 n][64 uint]
        float theta,
        ushort* __restrict__ hb,            // bf16 dense out (layers 0..2)
        float* __restrict__ fout) {         // f32 dense out (layer 3)
    __shared__ ushort As[64][136];
    __shared__ ushort Bs[128][72];
    const int tid  = threadIdx.x;
    const int lane = tid & 63;
    const int wave = tid >> 6;
    const int r0   = blockIdx.x * 64;
    const int q = lane >> 4;       // edge-parity quarter
    const int l = lane & 15;       // feature octet (8 bf16 = uint4)

    // stage B half 0 (k 0..63) — overlaps the gather phase
    #pragma unroll
    for (int p = 0; p < 4; ++p) {
        int idx = tid + p * 256;             // 0..1023
        int n = idx >> 3, kq = idx & 7;
        uint4 v = *reinterpret_cast<const uint4*>(wTc + n * 64 + kq * 4);
        *reinterpret_cast<uint4*>(&Bs[n][kq * 8]) = v;
    }

    // ---- gather phase: this wave owns LDS rows [wave*16, wave*16+16) ----
    for (int n0 = 0; n0 < 16; ++n0) {
        const int row  = wave * 16 + n0;
        const int node = r0 + row;
        int e0 = 0, e1 = 0;
        if (node < N_NODES) { e0 = rowptr[node]; e1 = rowptr[node + 1]; }

        float a0 = 0.f, a1 = 0.f, a2 = 0.f, a3 = 0.f;
        float a4 = 0.f, a5 = 0.f, a6 = 0.f, a7 = 0.f;
        for (int base = e0; base < e1; base += 64) {
            int m = e1 - base; if (m > 64) m = 64;
            int c = 0; float v = 0.f;
            if (lane < m) { c = cols[base + lane]; v = vals[base + lane]; }
            const int nt = (m + 3) >> 2;
            #pragma unroll 8
            for (int t = 0; t < nt; ++t) {
                int j = 4 * t + q;
                int jc = (j < m) ? j : 0;
                int   cj = __shfl(c, jc);
                float vj = __shfl(v, jc);
                if (j >= m) vj = 0.f;
                uint4 hv = hsrc[(size_t)cj * 16 + l];
                a0 = fmaf(vj, bflo(hv.x), a0);
                a1 = fmaf(vj, bfhi(hv.x), a1);
                a2 = fmaf(vj, bflo(hv.y), a2);
                a3 = fmaf(vj, bfhi(hv.y), a3);
                a4 = fmaf(vj, bflo(hv.z), a4);
                a5 = fmaf(vj, bfhi(hv.z), a5);
                a6 = fmaf(vj, bflo(hv.w), a6);
                a7 = fmaf(vj, bfhi(hv.w), a7);
            }
        }
        // combine the four quarters
        a0 += __shfl_xor(a0, 16); a1 += __shfl_xor(a1, 16);
        a2 += __shfl_xor(a2, 16); a3 += __shfl_xor(a3, 16);
        a4 += __shfl_xor(a4, 16); a5 += __shfl_xor(a5, 16);
        a6 += __shfl_xor(a6, 16); a7 += __shfl_xor(a7, 16);
        a0 += __shfl_xor(a0, 32); a1 += __shfl_xor(a1, 32);
        a2 += __shfl_xor(a2, 32); a3 += __shfl_xor(a3, 32);
        a4 += __shfl_xor(a4, 32); a5 += __shfl_xor(a5, 32);
        a6 += __shfl_xor(a6, 32); a7 += __shfl_xor(a7, 32);

        if (q == 0) {
            uint4 o;
            if (node < N_NODES) {
                uint4 h0v = h0b4[(size_t)node * 16 + l];
                o.x = bf16pack(0.9f * a0 + 0.1f * bflo(h0v.x), 0.9f * a1 + 0.1f * bfhi(h0v.x));
                o.y = bf16pack(0.9f * a2 + 0.1f * bflo(h0v.y), 0.9f * a3 + 0.1f * bfhi(h0v.y));
                o.z = bf16pack(0.9f * a4 + 0.1f * bflo(h0v.z), 0.9f * a5 + 0.1f * bfhi(h0v.z));
                o.w = bf16pack(0.9f * a6 + 0.1f * bflo(h0v.w), 0.9f * a7 + 0.1f * bfhi(h0v.w));
            } else {
                o.x = o.y = o.z = o.w = 0u;
            }
            *reinterpret_cast<uint4*>(&As[row][l * 8]) = o;
        }
    }
    __syncthreads();

    // ---- GEMM phase: 4 waves in 2x2, each 32 rows x 64 cols ----
    const int wr = wave >> 1, wc = wave & 1;
    f32x4 acc[2][4] = {};
    #pragma unroll
    for (int halfk = 0; halfk < 2; ++halfk) {
        if (halfk) {
            __syncthreads();
            #pragma unroll
            for (int p = 0; p < 4; ++p) {   // stage B half 1 (k 64..127)
                int idx = tid + p * 256;
                int n = idx >> 3, kq = idx & 7;
                uint4 v = *reinterpret_cast<const uint4*>(wTc + n * 64 + 32 + kq * 4);
                *reinterpret_cast<uint4*>(&Bs[n][kq * 8]) = v;
            }
            __syncthreads();
        }
        #pragma unroll
        for (int ks2 = 0; ks2 < 64; ks2 += 32) {
            #pragma unroll
            for (int mr = 0; mr < 2; ++mr) {
                bf16x8 a = *reinterpret_cast<const bf16x8*>(
                    &As[wr * 32 + mr * 16 + (lane & 15)][halfk * 64 + ks2 + (lane >> 4) * 8]);
                #pragma unroll
                for (int j = 0; j < 4; ++j) {
                    bf16x8 b = *reinterpret_cast<const bf16x8*>(
                        &Bs[wc * 64 + j * 16 + (lane & 15)][ks2 + (lane >> 4) * 8]);
                    acc[mr][j] = __builtin_amdgcn_mfma_f32_16x16x32_bf16(a, b, acc[mr][j], 0, 0, 0);
                }
            }
        }
    }

    // ---- epilogue: residual from LDS, relu, store ----
    const float om = 1.f - theta;
    #pragma unroll
    for (int mr = 0; mr < 2; ++mr) {
        const int rloc = wr * 32 + mr * 16 + ((lane >> 4) << 2);
        #pragma unroll
        for (int j = 0; j < 4; ++j) {
            int col = wc * 64 + j * 16 + (lane & 15);
            #pragma unroll
            for (int i = 0; i < 4; ++i) {
                int gr = r0 + rloc + i;
                if (gr < N_NODES) {
                    float s = bf16tof(As[rloc + i][col]);
                    float v = fmaxf(fmaf(theta, acc[mr][j][i], om * s), 0.f);
                    if (fout) fout[(size_t)gr * NHID + col] = v;
                    else      hb[(size_t)gr * NHID + col] = bf16s(v);
                }
            }
        }
    }
}

// ---------------------------------------------------------------------------
// final: logits = h @ fc2_w + b; out0 = log_softmax; out2 = [h, logits]
// ---------------------------------------------------------------------------
__global__ void final_kernel(const float* __restrict__ h, const float* __restrict__ w,
                             const float* __restrict__ b, float* __restrict__ out0,
                             float* __restrict__ out2) {
    __shared__ float hs[4][128];
    const int s = threadIdx.x >> 6;
    const int lane = threadIdx.x & 63;
    const int node = blockIdx.x * 4 + s;

    float h_lo = h[node * NHID + lane];
    float h_hi = h[node * NHID + 64 + lane];
    hs[s][lane] = h_lo;
    hs[s][64 + lane] = h_hi;
    __syncthreads();

    float logit = 0.f;
    if (lane < NCLASS) {
        logit = b[lane];
        #pragma unroll 8
        for (int k = 0; k < NHID; ++k)
            logit = fmaf(hs[s][k], w[k * NCLASS + lane], logit);
    }

    float mv = (lane < NCLASS) ? logit : -1e30f;
    #pragma unroll
    for (int m = 32; m; m >>= 1) mv = fmaxf(mv, __shfl_xor(mv, m));
    float ev = (lane < NCLASS) ? __expf(logit - mv) : 0.f;
    float sum = ev;
    #pragma unroll
    for (int m = 32; m; m >>= 1) sum += __shfl_xor(sum, m);
    float lse = mv + __logf(sum);

    if (lane < NCLASS) {
        out0[node * NCLASS + lane] = logit - lse;
        out2[node * 168 + 128 + lane] = logit;
    }
    out2[node * 168 + lane] = h_lo;
    out2[node * 168 + 64 + lane] = h_hi;
}

// ---------------------------------------------------------------------------
extern "C" void kernel_launch(void* const* d_in, const int* in_sizes, int n_in,
                              void* d_out, int out_size, void* d_ws, size_t ws_size,
                              hipStream_t stream) {
    const float* x      = (const float*)d_in[0];
    const int*   rows   = (const int*)  d_in[1];
    const int*   cols   = (const int*)  d_in[2];
    const float* vals   = (const float*)d_in[3];
    const float* fc1_w  = (const float*)d_in[4];
    const float* fc1_b  = (const float*)d_in[5];
    const float* conv_w = (const float*)d_in[6];
    const float* fc2_w  = (const float*)d_in[7];
    const float* fc2_b  = (const float*)d_in[8];
    float* out = (float*)d_out;

    const int nE = in_sizes[1];
    const size_t NH = (size_t)N_NODES * NHID;   // 12.8M elements

    // workspace layout
    char* p = (char*)d_ws;
    int*    rowptr = (int*)p;          p += 400128;          // 100001 ints, padded
    ushort* h0b    = (ushort*)p;       p += NH * 2;          // 25.6 MB
    ushort* bufA   = (ushort*)p;       p += NH * 2;          // 25.6 MB
    ushort* bufB   = (ushort*)p;       p += NH * 2;          // 25.6 MB
    ushort* wT1    = (ushort*)p;       p += 65536 * 2;       // 128 KB
    ushort* wTc    = (ushort*)p;       p += 65536 * 2;       // 128 KB

    // out regions
    float* out0 = out;                                  // [N,40]
    float* out1 = out + (size_t)N_NODES * NCLASS;       // [N,128] final h (f32)
    float* out2 = out1 + NH;                            // [N,168]

    prep_weights<<<256, 256, 0, stream>>>(fc1_w, conv_w, wT1, wTc);
    rowptr_kernel<<<(N_NODES + 1 + 255) / 256, 256, 0, stream>>>(rows, rowptr, nE);
    fc1_mfma<<<N_NODES / 32, 256, 0, stream>>>(x, (const uint*)wT1, fc1_b, h0b);

    const int nblk = (N_NODES + 63) / 64;
    const ushort* src = h0b;
    ushort* dsts[4] = { bufA, bufB, bufA, nullptr };
    for (int i = 0; i < 4; ++i) {
        float theta = logf(0.5f / (float)(i + 1) + 1.0f);
        spmm_layer<<<nblk, 256, 0, stream>>>(
            (const uint4*)src, (const uint4*)h0b, rowptr, cols, vals,
            (const uint*)(wTc + (size_t)i * 16384), theta,
            dsts[i], (i == 3) ? out1 : nullptr);
        src = dsts[i];
    }

    final_kernel<<<N_NODES / 4, 256, 0, stream>>>(out1, fc2_w, fc2_b, out0, out2);
}

// Round 8
// 486.129 us; speedup vs baseline: 2.7447x; 1.3169x over previous
//
#include <hip/hip_runtime.h>
#include <math.h>

#define N_NODES 100000
#define NFEAT 512
#define NHID 128
#define NCLASS 40

typedef unsigned int uint;
typedef unsigned short ushort;
typedef unsigned char uchar;
typedef short bf16x8 __attribute__((ext_vector_type(8)));
typedef float f32x4 __attribute__((ext_vector_type(4)));
typedef float f32x2 __attribute__((ext_vector_type(2)));

// f32 -> bf16 (RNE)
__device__ inline ushort bf16s(float a) {
    uint u = __float_as_uint(a);
    return (ushort)((u + 0x7fffu + ((u >> 16) & 1u)) >> 16);
}
__device__ inline uint bf16pack(float a, float b) {
    return (uint)bf16s(a) | ((uint)bf16s(b) << 16);
}
__device__ inline float bf16tof(ushort u) { return __uint_as_float(((uint)u) << 16); }
__device__ inline float bflo(uint u) { return __uint_as_float(u << 16); }
__device__ inline float bfhi(uint u) { return __uint_as_float(u & 0xffff0000u); }

// f32 -> fp8 e4m3 single byte (HW RNE)
__device__ inline uchar fp8byte(float v) {
    uint pk = __builtin_amdgcn_cvt_pk_fp8_f32(v, 0.f, 0u, false);
    return (uchar)(pk & 0xffu);
}

// ---------------------------------------------------------------------------
// weight prep: wT1[n][k] = bf16(fc1_w[k][n])   (128 x 512)
//              wTc[L][n][k] = bf16(conv_w[L][k][n])  (4 x 128 x 128)
// ---------------------------------------------------------------------------
__global__ void prep_weights(const float* __restrict__ fc1_w, const float* __restrict__ conv_w,
                             ushort* __restrict__ wT1, ushort* __restrict__ wTc) {
    int idx = blockIdx.x * 256 + threadIdx.x;   // 65536 total
    {   int n = idx >> 9, k = idx & 511;
        wT1[idx] = bf16s(fc1_w[k * NHID + n]); }
    {   int L = idx >> 14, rem = idx & 16383;
        int n = rem >> 7, k = rem & 127;
        wTc[idx] = bf16s(conv_w[L * 16384 + k * NHID + n]); }
}

// ---------------------------------------------------------------------------
// row_ptr[i] = lower_bound(rows, i)
// ---------------------------------------------------------------------------
__global__ void rowptr_kernel(const int* __restrict__ rows, int* __restrict__ rowptr, int nE) {
    int i = blockIdx.x * blockDim.x + threadIdx.x;
    if (i > N_NODES) return;
    int lo = 0, hi = nE;
    while (lo < hi) { int mid = (lo + hi) >> 1; if (rows[mid] < i) lo = mid + 1; else hi = mid; }
    rowptr[i] = lo;
}

// ---------------------------------------------------------------------------
// fc1 MFMA: h0 = relu(x @ W + b). Writes h0b (bf16, residual use) and
// hf8 (fp8, gather source for layer-0 spmm). BM=32, BN=128, K-step 64.
// ---------------------------------------------------------------------------
__global__ void __launch_bounds__(256) fc1_mfma(const float* __restrict__ x,
                                                const uint* __restrict__ wT1,
                                                const float* __restrict__ bias,
                                                ushort* __restrict__ h0b,
                                                uchar* __restrict__ hf8) {
    __shared__ ushort As[32][72];
    __shared__ ushort Bs[128][72];
    const int tid = threadIdx.x;
    const int lane = tid & 63;
    const int wave = tid >> 6;
    const int wr = wave >> 1, wc = wave & 1;
    const int r0 = blockIdx.x * 32;

    f32x4 acc[4] = {};

    for (int ks = 0; ks < NFEAT; ks += 64) {
        {   int row = tid >> 3, kq = tid & 7;
            const float* xp = x + (size_t)(r0 + row) * NFEAT + ks + kq * 8;
            float4 v0 = *reinterpret_cast<const float4*>(xp);
            float4 v1 = *reinterpret_cast<const float4*>(xp + 4);
            uint4 pk;
            pk.x = bf16pack(v0.x, v0.y); pk.y = bf16pack(v0.z, v0.w);
            pk.z = bf16pack(v1.x, v1.y); pk.w = bf16pack(v1.z, v1.w);
            *reinterpret_cast<uint4*>(&As[row][kq * 8]) = pk;
        }
        #pragma unroll
        for (int p = 0; p < 4; ++p) {
            int idx = tid + p * 256;
            int n = idx >> 3, q = idx & 7;
            uint4 w4 = *reinterpret_cast<const uint4*>(wT1 + n * 256 + (ks >> 1) + q * 4);
            *reinterpret_cast<uint4*>(&Bs[n][q * 8]) = w4;
        }
        __syncthreads();
        #pragma unroll
        for (int ks2 = 0; ks2 < 64; ks2 += 32) {
            bf16x8 a = *reinterpret_cast<const bf16x8*>(&As[wr * 16 + (lane & 15)][ks2 + (lane >> 4) * 8]);
            #pragma unroll
            for (int j = 0; j < 4; ++j) {
                bf16x8 b = *reinterpret_cast<const bf16x8*>(&Bs[wc * 64 + j * 16 + (lane & 15)][ks2 + (lane >> 4) * 8]);
                acc[j] = __builtin_amdgcn_mfma_f32_16x16x32_bf16(a, b, acc[j], 0, 0, 0);
            }
        }
        __syncthreads();
    }

    const int cb = wc * 64 + (lane & 15);
    const int rb = r0 + wr * 16 + ((lane >> 4) << 2);
    #pragma unroll
    for (int j = 0; j < 4; ++j) {
        int col = cb + j * 16;
        float bj = bias[col];
        #pragma unroll
        for (int i = 0; i < 4; ++i) {
            float v = fmaxf(acc[j][i] + bj, 0.f);
            h0b[(size_t)(rb + i) * NHID + col] = bf16s(v);
            hf8[(size_t)(rb + i) * NHID + col] = fp8byte(v);
        }
    }
}

// ---------------------------------------------------------------------------
// SpMM + residual: sb[n,:] = bf16(0.9 * sum_e vals[e]*fp8(h)[cols[e],:] + 0.1*h0b[n,:])
// One wave per node, FOUR 16-lane quarters process edges 4t+q; each quarter
// reads a full 128B fp8 row as uint2/lane. fp8 halves gather bytes; table is
// 12.8 MB (better per-XCD L2 residency). cols/vals nontemporal so edge
// metadata doesn't evict the gather table.
// ---------------------------------------------------------------------------
__global__ void __launch_bounds__(256) spmm_kernel(
        const uint2* __restrict__ h8,       // fp8 gather table [node][16 uint2]
        const uint4* __restrict__ h0b4,     // bf16 residual   [node][16 uint4]
        const int* __restrict__ rowptr,
        const int* __restrict__ cols,
        const float* __restrict__ vals,
        uint4* __restrict__ sb4) {          // bf16 out        [node][16 uint4]
    const int node = blockIdx.x * 4 + (threadIdx.x >> 6);
    const int lane = threadIdx.x & 63;
    const int q = lane >> 4;          // edge parity quarter
    const int l = lane & 15;          // feature octet: features 8l..8l+7

    const int e0 = rowptr[node], e1 = rowptr[node + 1];

    float a0 = 0.f, a1 = 0.f, a2 = 0.f, a3 = 0.f;
    float a4 = 0.f, a5 = 0.f, a6 = 0.f, a7 = 0.f;
    for (int base = e0; base < e1; base += 64) {
        int m = e1 - base; if (m > 64) m = 64;
        int c = 0; float v = 0.f;
        if (lane < m) {
            c = __builtin_nontemporal_load(cols + base + lane);
            v = __builtin_nontemporal_load(vals + base + lane);
        }
        const int nt = (m + 3) >> 2;
        #pragma unroll 8
        for (int t = 0; t < nt; ++t) {
            int j = 4 * t + q;
            int jc = (j < m) ? j : 0;
            int   cj = __shfl(c, jc);
            float vj = __shfl(v, jc);
            if (j >= m) vj = 0.f;
            uint2 hv = h8[(size_t)cj * 16 + l];
            f32x2 p0 = __builtin_amdgcn_cvt_pk_f32_fp8(hv.x, false);
            f32x2 p1 = __builtin_amdgcn_cvt_pk_f32_fp8(hv.x, true);
            f32x2 p2 = __builtin_amdgcn_cvt_pk_f32_fp8(hv.y, false);
            f32x2 p3 = __builtin_amdgcn_cvt_pk_f32_fp8(hv.y, true);
            a0 = fmaf(vj, p0.x, a0);
            a1 = fmaf(vj, p0.y, a1);
            a2 = fmaf(vj, p1.x, a2);
            a3 = fmaf(vj, p1.y, a3);
            a4 = fmaf(vj, p2.x, a4);
            a5 = fmaf(vj, p2.y, a5);
            a6 = fmaf(vj, p3.x, a6);
            a7 = fmaf(vj, p3.y, a7);
        }
    }
    // combine the four quarters
    a0 += __shfl_xor(a0, 16); a1 += __shfl_xor(a1, 16);
    a2 += __shfl_xor(a2, 16); a3 += __shfl_xor(a3, 16);
    a4 += __shfl_xor(a4, 16); a5 += __shfl_xor(a5, 16);
    a6 += __shfl_xor(a6, 16); a7 += __shfl_xor(a7, 16);
    a0 += __shfl_xor(a0, 32); a1 += __shfl_xor(a1, 32);
    a2 += __shfl_xor(a2, 32); a3 += __shfl_xor(a3, 32);
    a4 += __shfl_xor(a4, 32); a5 += __shfl_xor(a5, 32);
    a6 += __shfl_xor(a6, 32); a7 += __shfl_xor(a7, 32);

    if (q == 0) {
        uint4 h0v = h0b4[(size_t)node * 16 + l];
        uint4 o;
        o.x = bf16pack(0.9f * a0 + 0.1f * bflo(h0v.x), 0.9f * a1 + 0.1f * bfhi(h0v.x));
        o.y = bf16pack(0.9f * a2 + 0.1f * bflo(h0v.y), 0.9f * a3 + 0.1f * bfhi(h0v.y));
        o.z = bf16pack(0.9f * a4 + 0.1f * bflo(h0v.z), 0.9f * a5 + 0.1f * bfhi(h0v.z));
        o.w = bf16pack(0.9f * a6 + 0.1f * bflo(h0v.w), 0.9f * a7 + 0.1f * bfhi(h0v.w));
        sb4[(size_t)node * 16 + l] = o;
    }
}

// ---------------------------------------------------------------------------
// conv layer MFMA, BM=64: out = relu(theta*(S @ W) + (1-theta)*S).
// Layers 0..2 write ONLY the fp8 gather copy (12.8 MB); layer 3 writes f32 h.
// sb is padded by 64 rows so tail-block A-staging reads stay in bounds.
// ---------------------------------------------------------------------------
__global__ void __launch_bounds__(256) layer_mfma(const uint* __restrict__ sb,
                                                  const uint* __restrict__ wTc,
                                                  float theta,
                                                  uchar* __restrict__ hf8,
                                                  float* __restrict__ fout) {
    __shared__ ushort As[64][136];
    __shared__ ushort Bs[128][136];
    const int tid = threadIdx.x;
    const int lane = tid & 63;
    const int wave = tid >> 6;
    const int wr = wave >> 1, wc = wave & 1;
    const int r0 = blockIdx.x * 64;

    #pragma unroll
    for (int p = 0; p < 4; ++p) {   // stage A: 64 rows x 128 k
        int idx = tid + p * 256;
        int row = idx >> 4, kq = idx & 15;
        uint4 v = *reinterpret_cast<const uint4*>(sb + (size_t)(r0 + row) * 64 + kq * 4);
        *reinterpret_cast<uint4*>(&As[row][kq * 8]) = v;
    }
    #pragma unroll
    for (int p = 0; p < 8; ++p) {   // stage B: 128 n x 128 k
        int idx = tid + p * 256;
        int n = idx >> 4, kq = idx & 15;
        uint4 v = *reinterpret_cast<const uint4*>(wTc + n * 64 + kq * 4);
        *reinterpret_cast<uint4*>(&Bs[n][kq * 8]) = v;
    }
    __syncthreads();

    f32x4 acc[2][4] = {};
    #pragma unroll
    for (int ks = 0; ks < NHID; ks += 32) {
        #pragma unroll
        for (int mr = 0; mr < 2; ++mr) {
            bf16x8 a = *reinterpret_cast<const bf16x8*>(&As[wr * 32 + mr * 16 + (lane & 15)][ks + (lane >> 4) * 8]);
            #pragma unroll
            for (int j = 0; j < 4; ++j) {
                bf16x8 b = *reinterpret_cast<const bf16x8*>(&Bs[wc * 64 + j * 16 + (lane & 15)][ks + (lane >> 4) * 8]);
                acc[mr][j] = __builtin_amdgcn_mfma_f32_16x16x32_bf16(a, b, acc[mr][j], 0, 0, 0);
            }
        }
    }

    const float om = 1.f - theta;
    #pragma unroll
    for (int mr = 0; mr < 2; ++mr) {
        const int rloc = wr * 32 + mr * 16 + ((lane >> 4) << 2);
        #pragma unroll
        for (int j = 0; j < 4; ++j) {
            int col = wc * 64 + j * 16 + (lane & 15);
            #pragma unroll
            for (int i = 0; i < 4; ++i) {
                int gr = r0 + rloc + i;
                if (gr < N_NODES) {
                    float s = bf16tof(As[rloc + i][col]);
                    float v = fmaxf(fmaf(theta, acc[mr][j][i], om * s), 0.f);
                    if (fout) fout[(size_t)gr * NHID + col] = v;
                    else      hf8[(size_t)gr * NHID + col] = fp8byte(v);
                }
            }
        }
    }
}

// ---------------------------------------------------------------------------
// final: logits = h @ fc2_w + b; out0 = log_softmax; out2 = [h, logits]
// ---------------------------------------------------------------------------
__global__ void final_kernel(const float* __restrict__ h, const float* __restrict__ w,
                             const float* __restrict__ b, float* __restrict__ out0,
                             float* __restrict__ out2) {
    __shared__ float hs[4][128];
    const int s = threadIdx.x >> 6;
    const int lane = threadIdx.x & 63;
    const int node = blockIdx.x * 4 + s;

    float h_lo = h[node * NHID + lane];
    float h_hi = h[node * NHID + 64 + lane];
    hs[s][lane] = h_lo;
    hs[s][64 + lane] = h_hi;
    __syncthreads();

    float logit = 0.f;
    if (lane < NCLASS) {
        logit = b[lane];
        #pragma unroll 8
        for (int k = 0; k < NHID; ++k)
            logit = fmaf(hs[s][k], w[k * NCLASS + lane], logit);
    }

    float mv = (lane < NCLASS) ? logit : -1e30f;
    #pragma unroll
    for (int m = 32; m; m >>= 1) mv = fmaxf(mv, __shfl_xor(mv, m));
    float ev = (lane < NCLASS) ? __expf(logit - mv) : 0.f;
    float sum = ev;
    #pragma unroll
    for (int m = 32; m; m >>= 1) sum += __shfl_xor(sum, m);
    float lse = mv + __logf(sum);

    if (lane < NCLASS) {
        out0[node * NCLASS + lane] = logit - lse;
        out2[node * 168 + 128 + lane] = logit;
    }
    out2[node * 168 + lane] = h_lo;
    out2[node * 168 + 64 + lane] = h_hi;
}

// ---------------------------------------------------------------------------
extern "C" void kernel_launch(void* const* d_in, const int* in_sizes, int n_in,
                              void* d_out, int out_size, void* d_ws, size_t ws_size,
                              hipStream_t stream) {
    const float* x      = (const float*)d_in[0];
    const int*   rows   = (const int*)  d_in[1];
    const int*   cols   = (const int*)  d_in[2];
    const float* vals   = (const float*)d_in[3];
    const float* fc1_w  = (const float*)d_in[4];
    const float* fc1_b  = (const float*)d_in[5];
    const float* conv_w = (const float*)d_in[6];
    const float* fc2_w  = (const float*)d_in[7];
    const float* fc2_b  = (const float*)d_in[8];
    float* out = (float*)d_out;

    const int nE = in_sizes[1];
    const size_t NH = (size_t)N_NODES * NHID;   // 12.8M elements
    const size_t PAD = 64 * NHID;               // tail padding for BM=64 A-staging

    // workspace layout
    char* p = (char*)d_ws;
    int*    rowptr = (int*)p;          p += 400128;            // 100001 ints, padded
    ushort* h0b    = (ushort*)p;       p += NH * 2;            // 25.6 MB bf16 residual
    ushort* sb     = (ushort*)p;       p += (NH + PAD) * 2;    // 25.6 MB bf16 support
    uchar*  hf8    = (uchar*)p;        p += NH;                // 12.8 MB fp8 gather table
    ushort* wT1    = (ushort*)p;       p += 65536 * 2;         // 128 KB
    ushort* wTc    = (ushort*)p;       p += 65536 * 2;         // 128 KB

    // out regions
    float* out0 = out;                                  // [N,40]
    float* out1 = out + (size_t)N_NODES * NCLASS;       // [N,128] final h (f32)
    float* out2 = out1 + NH;                            // [N,168]

    prep_weights<<<256, 256, 0, stream>>>(fc1_w, conv_w, wT1, wTc);
    rowptr_kernel<<<(N_NODES + 1 + 255) / 256, 256, 0, stream>>>(rows, rowptr, nE);
    fc1_mfma<<<N_NODES / 32, 256, 0, stream>>>(x, (const uint*)wT1, fc1_b, h0b, hf8);

    for (int i = 0; i < 4; ++i) {
        float theta = logf(0.5f / (float)(i + 1) + 1.0f);
        spmm_kernel<<<N_NODES / 4, 256, 0, stream>>>(
            (const uint2*)hf8, (const uint4*)h0b, rowptr, cols, vals, (uint4*)sb);
        layer_mfma<<<(N_NODES + 63) / 64, 256, 0, stream>>>(
            (const uint*)sb, (const uint*)(wTc + (size_t)i * 16384), theta,
            hf8, (i == 3) ? out1 : nullptr);
    }

    final_kernel<<<N_NODES / 4, 256, 0, stream>>>(out1, fc2_w, fc2_b, out0, out2);
}

// Round 9
// 463.452 us; speedup vs baseline: 2.8790x; 1.0489x over previous
//
#include <hip/hip_runtime.h>
#include <math.h>

#define N_NODES 100000
#define NFEAT 512
#define NHID 128
#define NCLASS 40

typedef unsigned int uint;
typedef unsigned short ushort;
typedef unsigned char uchar;
typedef short bf16x8 __attribute__((ext_vector_type(8)));
typedef float f32x4 __attribute__((ext_vector_type(4)));
typedef float f32x2 __attribute__((ext_vector_type(2)));

// f32 -> bf16 (RNE)
__device__ inline ushort bf16s(float a) {
    uint u = __float_as_uint(a);
    return (ushort)((u + 0x7fffu + ((u >> 16) & 1u)) >> 16);
}
__device__ inline uint bf16pack(float a, float b) {
    return (uint)bf16s(a) | ((uint)bf16s(b) << 16);
}
__device__ inline float bf16tof(ushort u) { return __uint_as_float(((uint)u) << 16); }
__device__ inline float bflo(uint u) { return __uint_as_float(u << 16); }
__device__ inline float bfhi(uint u) { return __uint_as_float(u & 0xffff0000u); }

// f32 -> fp8 e4m3 single byte (HW RNE)
__device__ inline uchar fp8byte(float v) {
    uint pk = __builtin_amdgcn_cvt_pk_fp8_f32(v, 0.f, 0u, false);
    return (uchar)(pk & 0xffu);
}

// ---------------------------------------------------------------------------
// weight prep: wT1[n][k] = bf16(fc1_w[k][n])   (128 x 512)
//              wTc[L][n][k] = bf16(conv_w[L][k][n])  (4 x 128 x 128)
// ---------------------------------------------------------------------------
__global__ void prep_weights(const float* __restrict__ fc1_w, const float* __restrict__ conv_w,
                             ushort* __restrict__ wT1, ushort* __restrict__ wTc) {
    int idx = blockIdx.x * 256 + threadIdx.x;   // 65536 total
    {   int n = idx >> 9, k = idx & 511;
        wT1[idx] = bf16s(fc1_w[k * NHID + n]); }
    {   int L = idx >> 14, rem = idx & 16383;
        int n = rem >> 7, k = rem & 127;
        wTc[idx] = bf16s(conv_w[L * 16384 + k * NHID + n]); }
}

// ---------------------------------------------------------------------------
// row_ptr[i] = lower_bound(rows, i)
// ---------------------------------------------------------------------------
__global__ void rowptr_kernel(const int* __restrict__ rows, int* __restrict__ rowptr, int nE) {
    int i = blockIdx.x * blockDim.x + threadIdx.x;
    if (i > N_NODES) return;
    int lo = 0, hi = nE;
    while (lo < hi) { int mid = (lo + hi) >> 1; if (rows[mid] < i) lo = mid + 1; else hi = mid; }
    rowptr[i] = lo;
}

// ---------------------------------------------------------------------------
// fc1 MFMA: h0 = relu(x @ W + b). Writes h0b (bf16, residual use) and
// hf8 (fp8, gather source for layer-0 spmm). BM=32, BN=128, K-step 64.
// ---------------------------------------------------------------------------
__global__ void __launch_bounds__(256) fc1_mfma(const float* __restrict__ x,
                                                const uint* __restrict__ wT1,
                                                const float* __restrict__ bias,
                                                ushort* __restrict__ h0b,
                                                uchar* __restrict__ hf8) {
    __shared__ ushort As[32][72];
    __shared__ ushort Bs[128][72];
    const int tid = threadIdx.x;
    const int lane = tid & 63;
    const int wave = tid >> 6;
    const int wr = wave >> 1, wc = wave & 1;
    const int r0 = blockIdx.x * 32;

    f32x4 acc[4] = {};

    for (int ks = 0; ks < NFEAT; ks += 64) {
        {   int row = tid >> 3, kq = tid & 7;
            const float* xp = x + (size_t)(r0 + row) * NFEAT + ks + kq * 8;
            float4 v0 = *reinterpret_cast<const float4*>(xp);
            float4 v1 = *reinterpret_cast<const float4*>(xp + 4);
            uint4 pk;
            pk.x = bf16pack(v0.x, v0.y); pk.y = bf16pack(v0.z, v0.w);
            pk.z = bf16pack(v1.x, v1.y); pk.w = bf16pack(v1.z, v1.w);
            *reinterpret_cast<uint4*>(&As[row][kq * 8]) = pk;
        }
        #pragma unroll
        for (int p = 0; p < 4; ++p) {
            int idx = tid + p * 256;
            int n = idx >> 3, q = idx & 7;
            uint4 w4 = *reinterpret_cast<const uint4*>(wT1 + n * 256 + (ks >> 1) + q * 4);
            *reinterpret_cast<uint4*>(&Bs[n][q * 8]) = w4;
        }
        __syncthreads();
        #pragma unroll
        for (int ks2 = 0; ks2 < 64; ks2 += 32) {
            bf16x8 a = *reinterpret_cast<const bf16x8*>(&As[wr * 16 + (lane & 15)][ks2 + (lane >> 4) * 8]);
            #pragma unroll
            for (int j = 0; j < 4; ++j) {
                bf16x8 b = *reinterpret_cast<const bf16x8*>(&Bs[wc * 64 + j * 16 + (lane & 15)][ks2 + (lane >> 4) * 8]);
                acc[j] = __builtin_amdgcn_mfma_f32_16x16x32_bf16(a, b, acc[j], 0, 0, 0);
            }
        }
        __syncthreads();
    }

    const int cb = wc * 64 + (lane & 15);
    const int rb = r0 + wr * 16 + ((lane >> 4) << 2);
    #pragma unroll
    for (int j = 0; j < 4; ++j) {
        int col = cb + j * 16;
        float bj = bias[col];
        #pragma unroll
        for (int i = 0; i < 4; ++i) {
            float v = fmaxf(acc[j][i] + bj, 0.f);
            h0b[(size_t)(rb + i) * NHID + col] = bf16s(v);
            hf8[(size_t)(rb + i) * NHID + col] = fp8byte(v);
        }
    }
}

// ---------------------------------------------------------------------------
// SpMM + residual, shfl-free:
//   sb[n,:] = bf16(0.9 * sum_e vals[e]*fp8(h)[cols[e],:] + 0.1*h0b[n,:])
// One wave per node. Quarter q (16 lanes) walks edges e0+q, e0+q+4, ...
// All 16 lanes of a quarter load the SAME cols[e]/vals[e] address (hardware
// broadcasts; one line request) -- no ds_bpermute, no guard cndmask, no
// chunking. Gather row = 128B fp8 (uint2/lane). float2 accumulators invite
// v_pk_fma_f32. Cross-quarter combine at the end.
// ---------------------------------------------------------------------------
__global__ void __launch_bounds__(256) spmm_kernel(
        const uint2* __restrict__ h8,       // fp8 gather table [node][16 uint2]
        const uint4* __restrict__ h0b4,     // bf16 residual   [node][16 uint4]
        const int* __restrict__ rowptr,
        const int* __restrict__ cols,
        const float* __restrict__ vals,
        uint4* __restrict__ sb4) {          // bf16 out        [node][16 uint4]
    const int node = blockIdx.x * 4 + (threadIdx.x >> 6);
    const int lane = threadIdx.x & 63;
    const int q = lane >> 4;          // edge-parity quarter
    const int l = lane & 15;          // feature octet: features 8l..8l+7

    const int e0 = rowptr[node], e1 = rowptr[node + 1];

    f32x2 a0 = {0.f, 0.f}, a1 = {0.f, 0.f}, a2 = {0.f, 0.f}, a3 = {0.f, 0.f};
    #pragma unroll 4
    for (int e = e0 + q; e < e1; e += 4) {
        int   c = cols[e];            // same addr across the 16-lane quarter
        float v = vals[e];
        uint2 hv = h8[(size_t)c * 16 + l];
        f32x2 p0 = __builtin_amdgcn_cvt_pk_f32_fp8(hv.x, false);
        f32x2 p1 = __builtin_amdgcn_cvt_pk_f32_fp8(hv.x, true);
        f32x2 p2 = __builtin_amdgcn_cvt_pk_f32_fp8(hv.y, false);
        f32x2 p3 = __builtin_amdgcn_cvt_pk_f32_fp8(hv.y, true);
        f32x2 vv = {v, v};
        a0 += vv * p0;
        a1 += vv * p1;
        a2 += vv * p2;
        a3 += vv * p3;
    }

    // combine the four quarters (lane bits 4,5)
    #pragma unroll
    for (int d = 16; d <= 32; d <<= 1) {
        a0.x += __shfl_xor(a0.x, d); a0.y += __shfl_xor(a0.y, d);
        a1.x += __shfl_xor(a1.x, d); a1.y += __shfl_xor(a1.y, d);
        a2.x += __shfl_xor(a2.x, d); a2.y += __shfl_xor(a2.y, d);
        a3.x += __shfl_xor(a3.x, d); a3.y += __shfl_xor(a3.y, d);
    }

    if (q == 0) {
        uint4 h0v = h0b4[(size_t)node * 16 + l];
        uint4 o;
        o.x = bf16pack(0.9f * a0.x + 0.1f * bflo(h0v.x), 0.9f * a0.y + 0.1f * bfhi(h0v.x));
        o.y = bf16pack(0.9f * a1.x + 0.1f * bflo(h0v.y), 0.9f * a1.y + 0.1f * bfhi(h0v.y));
        o.z = bf16pack(0.9f * a2.x + 0.1f * bflo(h0v.z), 0.9f * a2.y + 0.1f * bfhi(h0v.z));
        o.w = bf16pack(0.9f * a3.x + 0.1f * bflo(h0v.w), 0.9f * a3.y + 0.1f * bfhi(h0v.w));
        sb4[(size_t)node * 16 + l] = o;
    }
}

// ---------------------------------------------------------------------------
// conv layer MFMA, BM=64: out = relu(theta*(S @ W) + (1-theta)*S).
// Layers 0..2 write ONLY the fp8 gather copy (12.8 MB); layer 3 writes f32 h.
// sb is padded by 64 rows so tail-block A-staging reads stay in bounds.
// ---------------------------------------------------------------------------
__global__ void __launch_bounds__(256) layer_mfma(const uint* __restrict__ sb,
                                                  const uint* __restrict__ wTc,
                                                  float theta,
                                                  uchar* __restrict__ hf8,
                                                  float* __restrict__ fout) {
    __shared__ ushort As[64][136];
    __shared__ ushort Bs[128][136];
    const int tid = threadIdx.x;
    const int lane = tid & 63;
    const int wave = tid >> 6;
    const int wr = wave >> 1, wc = wave & 1;
    const int r0 = blockIdx.x * 64;

    #pragma unroll
    for (int p = 0; p < 4; ++p) {   // stage A: 64 rows x 128 k
        int idx = tid + p * 256;
        int row = idx >> 4, kq = idx & 15;
        uint4 v = *reinterpret_cast<const uint4*>(sb + (size_t)(r0 + row) * 64 + kq * 4);
        *reinterpret_cast<uint4*>(&As[row][kq * 8]) = v;
    }
    #pragma unroll
    for (int p = 0; p < 8; ++p) {   // stage B: 128 n x 128 k
        int idx = tid + p * 256;
        int n = idx >> 4, kq = idx & 15;
        uint4 v = *reinterpret_cast<const uint4*>(wTc + n * 64 + kq * 4);
        *reinterpret_cast<uint4*>(&Bs[n][kq * 8]) = v;
    }
    __syncthreads();

    f32x4 acc[2][4] = {};
    #pragma unroll
    for (int ks = 0; ks < NHID; ks += 32) {
        #pragma unroll
        for (int mr = 0; mr < 2; ++mr) {
            bf16x8 a = *reinterpret_cast<const bf16x8*>(&As[wr * 32 + mr * 16 + (lane & 15)][ks + (lane >> 4) * 8]);
            #pragma unroll
            for (int j = 0; j < 4; ++j) {
                bf16x8 b = *reinterpret_cast<const bf16x8*>(&Bs[wc * 64 + j * 16 + (lane & 15)][ks + (lane >> 4) * 8]);
                acc[mr][j] = __builtin_amdgcn_mfma_f32_16x16x32_bf16(a, b, acc[mr][j], 0, 0, 0);
            }
        }
    }

    const float om = 1.f - theta;
    #pragma unroll
    for (int mr = 0; mr < 2; ++mr) {
        const int rloc = wr * 32 + mr * 16 + ((lane >> 4) << 2);
        #pragma unroll
        for (int j = 0; j < 4; ++j) {
            int col = wc * 64 + j * 16 + (lane & 15);
            #pragma unroll
            for (int i = 0; i < 4; ++i) {
                int gr = r0 + rloc + i;
                if (gr < N_NODES) {
                    float s = bf16tof(As[rloc + i][col]);
                    float v = fmaxf(fmaf(theta, acc[mr][j][i], om * s), 0.f);
                    if (fout) fout[(size_t)gr * NHID + col] = v;
                    else      hf8[(size_t)gr * NHID + col] = fp8byte(v);
                }
            }
        }
    }
}

// ---------------------------------------------------------------------------
// final: logits = h @ fc2_w + b; out0 = log_softmax; out2 = [h, logits]
// ---------------------------------------------------------------------------
__global__ void final_kernel(const float* __restrict__ h, const float* __restrict__ w,
                             const float* __restrict__ b, float* __restrict__ out0,
                             float* __restrict__ out2) {
    __shared__ float hs[4][128];
    const int s = threadIdx.x >> 6;
    const int lane = threadIdx.x & 63;
    const int node = blockIdx.x * 4 + s;

    float h_lo = h[node * NHID + lane];
    float h_hi = h[node * NHID + 64 + lane];
    hs[s][lane] = h_lo;
    hs[s][64 + lane] = h_hi;
    __syncthreads();

    float logit = 0.f;
    if (lane < NCLASS) {
        logit = b[lane];
        #pragma unroll 8
        for (int k = 0; k < NHID; ++k)
            logit = fmaf(hs[s][k], w[k * NCLASS + lane], logit);
    }

    float mv = (lane < NCLASS) ? logit : -1e30f;
    #pragma unroll
    for (int m = 32; m; m >>= 1) mv = fmaxf(mv, __shfl_xor(mv, m));
    float ev = (lane < NCLASS) ? __expf(logit - mv) : 0.f;
    float sum = ev;
    #pragma unroll
    for (int m = 32; m; m >>= 1) sum += __shfl_xor(sum, m);
    float lse = mv + __logf(sum);

    if (lane < NCLASS) {
        out0[node * NCLASS + lane] = logit - lse;
        out2[node * 168 + 128 + lane] = logit;
    }
    out2[node * 168 + lane] = h_lo;
    out2[node * 168 + 64 + lane] = h_hi;
}

// ---------------------------------------------------------------------------
extern "C" void kernel_launch(void* const* d_in, const int* in_sizes, int n_in,
                              void* d_out, int out_size, void* d_ws, size_t ws_size,
                              hipStream_t stream) {
    const float* x      = (const float*)d_in[0];
    const int*   rows   = (const int*)  d_in[1];
    const int*   cols   = (const int*)  d_in[2];
    const float* vals   = (const float*)d_in[3];
    const float* fc1_w  = (const float*)d_in[4];
    const float* fc1_b  = (const float*)d_in[5];
    const float* conv_w = (const float*)d_in[6];
    const float* fc2_w  = (const float*)d_in[7];
    const float* fc2_b  = (const float*)d_in[8];
    float* out = (float*)d_out;

    const int nE = in_sizes[1];
    const size_t NH = (size_t)N_NODES * NHID;   // 12.8M elements
    const size_t PAD = 64 * NHID;               // tail padding for BM=64 A-staging

    // workspace layout
    char* p = (char*)d_ws;
    int*    rowptr = (int*)p;          p += 400128;            // 100001 ints, padded
    ushort* h0b    = (ushort*)p;       p += NH * 2;            // 25.6 MB bf16 residual
    ushort* sb     = (ushort*)p;       p += (NH + PAD) * 2;    // 25.6 MB bf16 support
    uchar*  hf8    = (uchar*)p;        p += NH;                // 12.8 MB fp8 gather table
    ushort* wT1    = (ushort*)p;       p += 65536 * 2;         // 128 KB
    ushort* wTc    = (ushort*)p;       p += 65536 * 2;         // 128 KB

    // out regions
    float* out0 = out;                                  // [N,40]
    float* out1 = out + (size_t)N_NODES * NCLASS;       // [N,128] final h (f32)
    float* out2 = out1 + NH;                            // [N,168]

    prep_weights<<<256, 256, 0, stream>>>(fc1_w, conv_w, wT1, wTc);
    rowptr_kernel<<<(N_NODES + 1 + 255) / 256, 256, 0, stream>>>(rows, rowptr, nE);
    fc1_mfma<<<N_NODES / 32, 256, 0, stream>>>(x, (const uint*)wT1, fc1_b, h0b, hf8);

    for (int i = 0; i < 4; ++i) {
        float theta = logf(0.5f / (float)(i + 1) + 1.0f);
        spmm_kernel<<<N_NODES / 4, 256, 0, stream>>>(
            (const uint2*)hf8, (const uint4*)h0b, rowptr, cols, vals, (uint4*)sb);
        layer_mfma<<<(N_NODES + 63) / 64, 256, 0, stream>>>(
            (const uint*)sb, (const uint*)(wTc + (size_t)i * 16384), theta,
            hf8, (i == 3) ? out1 : nullptr);
    }

    final_kernel<<<N_NODES / 4, 256, 0, stream>>>(out1, fc2_w, fc2_b, out0, out2);
}